// Round 9
// baseline (43.245 us; speedup 1.0000x reference)
//
#include <hip/hip_runtime.h>
#include <math.h>

// Problem constants (from reference): B=8, M=N=4096, C=3, f32.
constexpr int NB   = 8;
constexpr int M    = 4096;
constexpr int N    = 4096;
constexpr int NS   = 32;           // segments of the N loop
constexpr int SEG  = N / NS;       // 128 points per segment
constexpr int TPB  = 512;          // 8 waves/block
constexpr int KA   = 8;            // a-points per thread; TPB*KA = 4096 = M
constexpr int RTPB = 256;          // k2a threads
constexpr int GPB  = 4;            // k2a blocks per group g
constexpr int CPB  = (M / 4) / GPB;// float4 columns per k2a block = 256
constexpr int TTPB = 256;          // k0 threads

// k0: bt[g][n] = (-2x, -2y, -2z, |b|^2) of dir g's TARGET set (dir0->set2).
// 2*NB*N points; coalesced float4 stores. ~1-2 us.
__global__ __launch_bounds__(TTPB) void hausdorff_transform_kernel(
    const float* __restrict__ set1, const float* __restrict__ set2,
    float4* __restrict__ bt)
{
    int i     = blockIdx.x * TTPB + threadIdx.x;   // over 2*NB*N
    int n     = i & (N - 1);
    int batch = (i >> 12) & (NB - 1);
    int dir   = i >> 15;
    const float* src = (dir ? set1 : set2) + ((size_t)batch * N + n) * 3;
    float x = src[0], y = src[1], z = src[2];
    float sb = fmaf(z, z, fmaf(y, y, x * x));
    bt[i] = make_float4(-2.0f * x, -2.0f * y, -2.0f * z, sb);
}

// Stage 1: pmin[g][seg][a] = sa + min_{n in seg} (sb - 2 a.b)
// B-points are WAVE-UNIFORM -> read bt[n] at a block-uniform address from a
// __restrict const pointer so the compiler emits s_load (SMEM pipe, SGPR
// operands). This takes the broadcast off the LDS/VMEM pipes, whose ~15 cyc
// per-CU cost was pipe-balanced with VALU and serializing (R1/R7 fits).
// No LDS, no __syncthreads. VALU: 3 fma + 1 min / pair + 1 v_mov / n.
__global__ __launch_bounds__(TPB, 2) void hausdorff_min_kernel(
    const float* __restrict__ set1, const float* __restrict__ set2,
    const float4* __restrict__ bt, float* __restrict__ pmin)
{
    int bid   = blockIdx.x;
    int seg   = bid & (NS - 1);
    int g     = bid >> 5;          // dir*NB + batch
    int batch = g & (NB - 1);
    int dir   = g >> 3;
    int tid   = threadIdx.x;

    const float* A = dir ? set2 : set1;            // query set
    const float4* bseg = bt + (size_t)g * N + (size_t)seg * SEG;  // uniform

    // This thread's KA query points in registers (block covers all of M).
    float ax[KA], ay[KA], az[KA], dmin[KA];
    const float* abase = A + (size_t)batch * M * 3;
    #pragma unroll
    for (int k = 0; k < KA; ++k) {
        int ai = k * TPB + tid;
        ax[k] = abase[ai*3+0];
        ay[k] = abase[ai*3+1];
        az[k] = abase[ai*3+2];
        dmin[k] = 3.4e38f;
    }

    #pragma unroll 8
    for (int n = 0; n < SEG; ++n) {
        float4 b = bseg[n];            // uniform -> s_load, SGPR-resident
        #pragma unroll
        for (int k = 0; k < KA; ++k) {
            float d2 = fmaf(ax[k], b.x, fmaf(ay[k], b.y, fmaf(az[k], b.z, b.w)));
            dmin[k] = fminf(dmin[k], d2);
        }
    }

    // Epilogue: add query-constant |a|^2, coalesced stores [g][seg][a].
    float* outp = pmin + ((size_t)g * NS + seg) * M;
    #pragma unroll
    for (int k = 0; k < KA; ++k) {
        int ai = k * TPB + tid;
        float sa = fmaf(az[k], az[k], fmaf(ay[k], ay[k], ax[k] * ax[k]));
        outp[ai] = sa + dmin[k];
    }
}

// Stage 2a: grid = 16*GPB = 64 blocks x 256 threads; one float4-column per
// thread (coalesced), min over 32 segs, clamp, sqrt, block-sum -> partial.
__global__ __launch_bounds__(RTPB) void hausdorff_partial_kernel(
    const float* __restrict__ pmin, float* __restrict__ partial)
{
    int bid = blockIdx.x;
    int grp = bid & (GPB - 1);
    int g   = bid >> 2;            // dir*NB + batch
    int t   = threadIdx.x;
    int col = grp * CPB + t;       // float4 column, 0..1023

    const float4* base = reinterpret_cast<const float4*>(
        pmin + (size_t)g * NS * M) + col;

    float4 mn = make_float4(3.4e38f, 3.4e38f, 3.4e38f, 3.4e38f);
    #pragma unroll 8
    for (int s = 0; s < NS; ++s) {
        float4 v = base[(size_t)s * (M/4)];
        mn.x = fminf(mn.x, v.x); mn.y = fminf(mn.y, v.y);
        mn.z = fminf(mn.z, v.z); mn.w = fminf(mn.w, v.w);
    }
    float sum = sqrtf(fmaxf(mn.x, 0.0f)) + sqrtf(fmaxf(mn.y, 0.0f))
              + sqrtf(fmaxf(mn.z, 0.0f)) + sqrtf(fmaxf(mn.w, 0.0f));

    for (int off = 32; off > 0; off >>= 1)
        sum += __shfl_down(sum, off, 64);

    __shared__ float red[RTPB / 64];
    if ((t & 63) == 0) red[t >> 6] = sum;
    __syncthreads();
    if (t == 0) {
        float tt = 0.0f;
        #pragma unroll
        for (int w = 0; w < RTPB / 64; ++w) tt += red[w];
        partial[bid] = tt;         // partial[g*GPB + grp]
    }
}

// Stage 2b: out[b] = (sum over dirs & grps) / M.  1 block, 64 threads.
__global__ __launch_bounds__(64) void hausdorff_final_kernel(
    const float* __restrict__ partial, float* __restrict__ out)
{
    int t = threadIdx.x;
    if (t < NB) {
        float s = 0.0f;
        #pragma unroll
        for (int j = 0; j < GPB; ++j)
            s += partial[t * GPB + j] + partial[(NB + t) * GPB + j];
        out[t] = s * (1.0f / (float)M);
    }
}

extern "C" void kernel_launch(void* const* d_in, const int* in_sizes, int n_in,
                              void* d_out, int out_size, void* d_ws, size_t ws_size,
                              hipStream_t stream) {
    const float* set1 = (const float*)d_in[0];
    const float* set2 = (const float*)d_in[1];
    float* out     = (float*)d_out;

    char* ws = (char*)d_ws;
    float*  pmin    = (float*)ws;                              // 8 MiB
    float4* bt      = (float4*)(ws + (size_t)2*NB*NS*M*4);     // 512 KiB
    float*  partial = (float*)(ws + (size_t)2*NB*NS*M*4
                                  + (size_t)2*NB*N*16);        // 64 floats

    hausdorff_transform_kernel<<<2 * NB * N / TTPB, TTPB, 0, stream>>>(
        set1, set2, bt);
    hausdorff_min_kernel<<<2 * NB * NS, TPB, 0, stream>>>(
        set1, set2, bt, pmin);
    hausdorff_partial_kernel<<<2 * NB * GPB, RTPB, 0, stream>>>(pmin, partial);
    hausdorff_final_kernel<<<1, 64, 0, stream>>>(partial, out);
}

// Round 10
// 29.543 us; speedup vs baseline: 1.4638x; 1.4638x over previous
//
#include <hip/hip_runtime.h>
#include <hip/hip_bf16.h>
#include <math.h>

// Problem: B=8, M=N=4096, C=3, f32. Avg-Hausdorff (Chamfer), out (8,).
// Strategy: d2(a,b) = sa + (sb - 2 a.b). The paren term is a rank-16 bf16
// matmul via fp32->bf16 hi/lo splitting (error ~2e-4 abs), done with
// mfma_f32_32x32x16_bf16; sa is folded in as the MFMA C-operand.
constexpr int NB = 8;
constexpr int NPTS = 4096;
constexpr int KDIM = 16;           // K slots per pair

typedef __attribute__((ext_vector_type(8)))  short  short8;
typedef __attribute__((ext_vector_type(16))) float  f32x16;

__device__ inline unsigned short f2bf(float v) {
    __hip_bfloat16 t = __float2bfloat16(v);
    return *reinterpret_cast<unsigned short*>(&t);
}
__device__ inline float bf2f(unsigned short u) {
    __hip_bfloat16 t = *reinterpret_cast<__hip_bfloat16*>(&u);
    return __bfloat162float(t);
}

// k0: encode panels. For each set s (0=set1,1=set2), batch b, point i:
//  A-row (query): [ahx ahy ahz alx aly alz 1 1 ahx ahy ahz 0 0 0 0 0]
//  B-row (target): t=-2p: [thx thy thz thx thy thz sqh sql tlx tly tlz 0...]
//  Sa[i] = |p|^2 (fp32, exact)
__global__ __launch_bounds__(256) void prep_kernel(
    const float* __restrict__ s1, const float* __restrict__ s2,
    unsigned short* __restrict__ Ap, unsigned short* __restrict__ Bp,
    float* __restrict__ Sa)
{
    int i = blockIdx.x * 256 + threadIdx.x;      // over 2*NB*NPTS = 65536
    int s = i >> 15;
    const float* p = (s ? s2 : s1) + (size_t)(i & 32767) * 3;
    float x = p[0], y = p[1], z = p[2];
    float sq = fmaf(z, z, fmaf(y, y, x * x));

    unsigned short ahx = f2bf(x), ahy = f2bf(y), ahz = f2bf(z);
    unsigned short alx = f2bf(x - bf2f(ahx));
    unsigned short aly = f2bf(y - bf2f(ahy));
    unsigned short alz = f2bf(z - bf2f(ahz));
    unsigned short one = 0x3F80;                 // bf16(1.0)

    float tx = -2.0f * x, ty = -2.0f * y, tz = -2.0f * z;
    unsigned short thx = f2bf(tx), thy = f2bf(ty), thz = f2bf(tz);
    unsigned short tlx = f2bf(tx - bf2f(thx));
    unsigned short tly = f2bf(ty - bf2f(thy));
    unsigned short tlz = f2bf(tz - bf2f(thz));
    unsigned short sqh = f2bf(sq);
    unsigned short sql = f2bf(sq - bf2f(sqh));

    short8 aLo = {(short)ahx,(short)ahy,(short)ahz,(short)alx,(short)aly,(short)alz,(short)one,(short)one};
    short8 aHi = {(short)ahx,(short)ahy,(short)ahz,0,0,0,0,0};
    short8 bLo = {(short)thx,(short)thy,(short)thz,(short)thx,(short)thy,(short)thz,(short)sqh,(short)sql};
    short8 bHi = {(short)tlx,(short)tly,(short)tlz,0,0,0,0,0};

    *(short8*)(void*)(Ap + (size_t)i * KDIM)     = aLo;
    *(short8*)(void*)(Ap + (size_t)i * KDIM + 8) = aHi;
    *(short8*)(void*)(Bp + (size_t)i * KDIM)     = bLo;
    *(short8*)(void*)(Bp + (size_t)i * KDIM + 8) = bHi;
    Sa[i] = sq;
}

// k1: grid = 16 groups x 16 m-blocks x 2 n-segs = 512 blocks, 256 thr (4 waves).
// Wave owns 2 m-tiles (64 rows); block covers 256 m-rows x 2048 n.
// Per n-tile pair: 2 ds_read_b128 + 4 mfma(C=sa) + 32 fused min3.
// Epilogue: 5-step shuffle-min over n-cols, lane c==0 stores rowmin.
__global__ __launch_bounds__(256, 2) void mfma_min_kernel(
    const unsigned short* __restrict__ Ap, const unsigned short* __restrict__ Bp,
    const float* __restrict__ Sa, float* __restrict__ pmin)
{
    __shared__ unsigned short blds[1024 * KDIM];   // 32 KB chunk (1024 n-rows)

    int bid  = blockIdx.x;
    int nseg = bid & 1;
    int mblk = (bid >> 1) & 15;
    int g    = bid >> 5;               // dir*8 + batch
    int b    = g & 7, dir = g >> 3;
    int qs   = dir, ts = 1 - dir;      // query set / target set index

    int tid = threadIdx.x;
    int wid = tid >> 6, lane = tid & 63;
    int c = lane & 31, h = lane >> 5;

    const unsigned short* Abase = Ap + (size_t)(qs * NB + b) * NPTS * KDIM;
    const unsigned short* Bbase = Bp + ((size_t)(ts * NB + b) * NPTS + (size_t)nseg * 2048) * KDIM;
    const float* sab = Sa + (size_t)(qs * NB + b) * NPTS;

    int mbase = mblk * 256 + wid * 64;

    short8 afr[2]; f32x16 csa[2]; f32x16 acc[2];
    #pragma unroll
    for (int mt = 0; mt < 2; ++mt) {
        int mrow = mbase + mt * 32 + c;
        afr[mt] = *(const short8*)(const void*)(Abase + (size_t)mrow * KDIM + h * 8);
        #pragma unroll
        for (int r = 0; r < 16; ++r) {
            int row = (r & 3) + 8 * (r >> 2) + 4 * h;
            csa[mt][r] = sab[mbase + mt * 32 + row];
            acc[mt][r] = 3.4e38f;
        }
    }

    for (int chunk = 0; chunk < 2; ++chunk) {
        __syncthreads();               // LDS reuse guard
        // Stage 1024 rows (32 KB): 2048 short8's / 256 threads = 8 each.
        #pragma unroll
        for (int r = 0; r < 8; ++r) {
            int u = r * 256 + tid;     // short8 index
            *(short8*)(void*)&blds[u * 8] =
                *(const short8*)(const void*)(Bbase + (size_t)chunk * 1024 * KDIM + (size_t)u * 8);
        }
        __syncthreads();

        #pragma unroll 2
        for (int ntp = 0; ntp < 16; ++ntp) {   // 32 n-tiles, in pairs
            short8 b0 = *(const short8*)(const void*)&blds[((2*ntp  ) * 32 + c) * KDIM + h * 8];
            short8 b1 = *(const short8*)(const void*)&blds[((2*ntp+1) * 32 + c) * KDIM + h * 8];
            #pragma unroll
            for (int mt = 0; mt < 2; ++mt) {
                f32x16 d0 = __builtin_amdgcn_mfma_f32_32x32x16_bf16(afr[mt], b0, csa[mt], 0, 0, 0);
                f32x16 d1 = __builtin_amdgcn_mfma_f32_32x32x16_bf16(afr[mt], b1, csa[mt], 0, 0, 0);
                #pragma unroll
                for (int r = 0; r < 16; ++r)
                    acc[mt][r] = fminf(fminf(acc[mt][r], d0[r]), d1[r]);   // v_min3
            }
        }
    }

    // Cross-lane min over the 32 n-columns (lanes within same h-half).
    #pragma unroll
    for (int mt = 0; mt < 2; ++mt) {
        #pragma unroll
        for (int r = 0; r < 16; ++r) {
            float v = acc[mt][r];
            v = fminf(v, __shfl_xor(v, 1));
            v = fminf(v, __shfl_xor(v, 2));
            v = fminf(v, __shfl_xor(v, 4));
            v = fminf(v, __shfl_xor(v, 8));
            v = fminf(v, __shfl_xor(v, 16));
            if (c == 0) {
                int row = (r & 3) + 8 * (r >> 2) + 4 * h;
                pmin[((size_t)g * 2 + nseg) * NPTS + mbase + mt * 32 + row] = v;
            }
        }
    }
}

// k2a: 64 blocks (16 g x 4): min over 2 segs, clamp, sqrt, block-sum.
__global__ __launch_bounds__(256) void reduce_kernel(
    const float* __restrict__ pmin, float* __restrict__ partial)
{
    int bid = blockIdx.x;
    int q = bid & 3, g = bid >> 2;
    int t = threadIdx.x;

    const float4* p0 = (const float4*)(pmin + (size_t)g * 2 * NPTS) + q * 256 + t;
    const float4* p1 = (const float4*)(pmin + ((size_t)g * 2 + 1) * NPTS) + q * 256 + t;
    float4 a = *p0, bb = *p1;
    float s = sqrtf(fmaxf(fminf(a.x, bb.x), 0.0f))
            + sqrtf(fmaxf(fminf(a.y, bb.y), 0.0f))
            + sqrtf(fmaxf(fminf(a.z, bb.z), 0.0f))
            + sqrtf(fmaxf(fminf(a.w, bb.w), 0.0f));

    for (int off = 32; off > 0; off >>= 1)
        s += __shfl_down(s, off, 64);

    __shared__ float red[4];
    if ((t & 63) == 0) red[t >> 6] = s;
    __syncthreads();
    if (t == 0) partial[bid] = red[0] + red[1] + red[2] + red[3];
}

// k2b: out[b] = (dir0 + dir1 sums) / M
__global__ __launch_bounds__(64) void final_kernel(
    const float* __restrict__ partial, float* __restrict__ out)
{
    int t = threadIdx.x;
    if (t < NB) {
        float s = 0.0f;
        #pragma unroll
        for (int j = 0; j < 4; ++j)
            s += partial[t * 4 + j] + partial[(NB + t) * 4 + j];
        out[t] = s * (1.0f / (float)NPTS);
    }
}

extern "C" void kernel_launch(void* const* d_in, const int* in_sizes, int n_in,
                              void* d_out, int out_size, void* d_ws, size_t ws_size,
                              hipStream_t stream) {
    const float* set1 = (const float*)d_in[0];
    const float* set2 = (const float*)d_in[1];
    float* out = (float*)d_out;

    char* ws = (char*)d_ws;
    unsigned short* Ap = (unsigned short*)ws;                    // 2 MiB
    unsigned short* Bp = (unsigned short*)(ws + (2u << 20));     // 2 MiB
    float* Sa      = (float*)(ws + (4u << 20));                  // 256 KiB
    float* pmin    = (float*)(ws + (4u << 20) + (256u << 10));   // 512 KiB
    float* partial = (float*)(ws + (4u << 20) + (768u << 10));   // 64 floats

    prep_kernel<<<2 * NB * NPTS / 256, 256, 0, stream>>>(set1, set2, Ap, Bp, Sa);
    mfma_min_kernel<<<512, 256, 0, stream>>>(Ap, Bp, Sa, pmin);
    reduce_kernel<<<64, 256, 0, stream>>>(pmin, partial);
    final_kernel<<<1, 64, 0, stream>>>(partial, out);
}